// Round 13
// baseline (475.912 us; speedup 1.0000x reference)
//
#include <hip/hip_runtime.h>
#include <hip/hip_bf16.h>

typedef __hip_bfloat16 bf16;
typedef short short8 __attribute__((ext_vector_type(8)));
typedef float floatx4 __attribute__((ext_vector_type(4)));

#define BDIM 2048   // E*S
#define HDIM 512
#define LDIM 20
#define CDIM 32

__device__ __forceinline__ float sigm(float x) { return 1.0f / (1.0f + expf(-x)); }

// async global->LDS, 16 B per lane; lds base must be wave-uniform, HW strides by lane*16
__device__ __forceinline__ void ll16(const short* g, short* l)
{
    __builtin_amdgcn_global_load_lds(
        (const __attribute__((address_space(1))) void*)g,
        (__attribute__((address_space(3))) void*)l, 16, 0, 0);
}
#define WAITVM(N) asm volatile("s_waitcnt vmcnt(" #N ")" ::: "memory")

// ---------------------------------------------------------------------------
// 128x128 bf16 MFMA tile with global_load_lds staging (m97 structure):
// linear LDS chunks [128][32] (64B rows -> 2-way bank aliasing, free).
// BK=64 rejected: 128B rows would be a 16-way conflict and ll16 can't pad.
// ---------------------------------------------------------------------------
__device__ __forceinline__ void gemm_tile_ll(
    const short* __restrict__ A, int lda,
    const short* __restrict__ Bt, int ldb,
    int K, short* lds, floatx4 (&acc)[4][4], int tid)
{
    short* As = lds;             // [128][32] linear
    short* Bs = lds + 128 * 32;  // [128][32] linear
    const int wave = tid >> 6, lane = tid & 63;
    const int wm = wave & 1, wn = wave >> 1;
    const int m16 = lane & 15, quad = lane >> 4;
    const int lrow = lane >> 2;          // 0..15 (16 rows per wave-issue)
    const int lcol = (lane & 3) * 8;     // 4 x 16B per row

    for (int k0 = 0; k0 < K; k0 += 32) {
        __syncthreads();                 // previous chunk's reads retired
#pragma unroll
        for (int seg = 0; seg < 2; ++seg) {
            const int sg = wave + seg * 4;   // 0..7: 16-row segment
            ll16(A  + (size_t)(sg * 16 + lrow) * lda + k0 + lcol, As + sg * 512);
            ll16(Bt + (size_t)(sg * 16 + lrow) * ldb + k0 + lcol, Bs + sg * 512);
        }
        WAITVM(0);
        __syncthreads();                 // chunk staged by all waves
        short8 af[4], bfr[4];
#pragma unroll
        for (int i = 0; i < 4; ++i)
            af[i] = *(short8*)(As + (wm * 64 + i * 16 + m16) * 32 + quad * 8);
#pragma unroll
        for (int j = 0; j < 4; ++j)
            bfr[j] = *(short8*)(Bs + (wn * 64 + j * 16 + m16) * 32 + quad * 8);
#pragma unroll
        for (int i = 0; i < 4; ++i)
#pragma unroll
            for (int j = 0; j < 4; ++j)
                acc[i][j] = __builtin_amdgcn_mfma_f32_16x16x32_bf16(
                    af[i], bfr[j], acc[i][j], 0, 0, 0);
    }
}

// ---------------------------------------------------------------------------
// Merged prep: xb cast | swzW (h-half) | wc reorder | wh transpose |
// swzX (x-half, for in-GRU gx) | out_lp zero | ctr zero. One launch.
// ---------------------------------------------------------------------------
__global__ __launch_bounds__(256) void k_prep_all(
    const float* __restrict__ x, bf16* __restrict__ xb,
    const float* __restrict__ Wr, const float* __restrict__ Wz,
    const float* __restrict__ Wn, bf16* __restrict__ Wfrag,
    const float* __restrict__ w1, const float* __restrict__ w3,
    const float* __restrict__ w5, const float* __restrict__ w7,
    bf16* __restrict__ wt,
    const float* __restrict__ Wmu, const float* __restrict__ Wstd,
    bf16* __restrict__ Wh_t, bf16* __restrict__ WxF,
    float* __restrict__ out_lp, unsigned* __restrict__ ctr)
{
    const int bid = blockIdx.x, tid = threadIdx.x;
    if (bid < 4096) {                       // xb: x -> bf16
        int i = bid * 256 + tid;
        xb[i] = (bf16)x[i];
    } else if (bid < 7168) {                // swzW: h-half GRU weights
        int idx = (bid - 4096) * 256 + tid; // 0..786431
        int e = idx & 7, lane = (idx >> 3) & 63;
        int t2 = idx >> 9;                  // (j*16 + kc)*6 + f
        int f = t2 % 6, jk = t2 / 6;
        int kc = jk & 15, j = jk >> 4;
        int ftype = f >> 1;
        int col = j * 32 + (f & 1) * 16 + (lane & 15);
        int k = kc * 32 + ((lane >> 4) << 3) + e;
        const float* W = (ftype == 0) ? Wr : (ftype == 1) ? Wz : Wn;
        Wfrag[idx] = (bf16)W[(size_t)(512 + k) * 512 + col];
    } else if (bid < 11264) {               // wc: conv weights reorder
        int idx = (bid - 7168) * 256 + tid;
        int g, base;
        if (idx < 65536)       { g = 0; base = 0;      }
        else if (idx < 262144) { g = 1; base = 65536;  }
        else if (idx < 589824) { g = 2; base = 262144; }
        else                   { g = 3; base = 589824; }
        int rel = idx - base;
        int k = 2 * g + 1;
        int ci = rel & 511;
        int t2 = rel >> 9;
        int co = t2 & 127;
        int tap = t2 >> 7;
        const float* w = (g == 0) ? w1 : (g == 1) ? w3 : (g == 2) ? w5 : w7;
        wt[idx] = (bf16)w[((size_t)co * 512 + ci) * k + tap];
    } else if (bid < 11392) {               // wh: [Wmu|Wstd] -> [64][512]
        int idx = (bid - 11264) * 256 + tid; // 0..32767
        int n = idx >> 9, k = idx & 511;
        float v = (n < 32) ? Wmu[(size_t)k * 32 + n]
                           : Wstd[(size_t)k * 32 + (n - 32)];
        Wh_t[idx] = (bf16)v;
    } else if (bid < 14464) {               // swzX: x-half weights (gx in GRU)
        int idx = (bid - 11392) * 256 + tid; // 0..786431
        int e = idx & 7, lane = (idx >> 3) & 63;
        int t2 = idx >> 9;
        int f = t2 % 6, jk = t2 / 6;
        int kc = jk & 15, j = jk >> 4;
        int ftype = f >> 1;
        int col = j * 32 + (f & 1) * 16 + (lane & 15);
        int k = kc * 32 + ((lane >> 4) << 3) + e;   // rows 0..511 (x-half)
        const float* W = (ftype == 0) ? Wr : (ftype == 1) ? Wz : Wn;
        WxF[idx] = (bf16)W[(size_t)k * 512 + col];
    } else if (bid < 14472) {               // out_lp zero (2048 floats)
        out_lp[(bid - 14464) * 256 + tid] = 0.0f;
    } else {                                // ctr zero (512 dwords)
        ctr[tid * 2]     = 0u;
        ctr[tid * 2 + 1] = 0u;
    }
}

// ---------------------------------------------------------------------------
// GRU v15 = v9 (PROVEN sync, closed) + FUSED gx: each block computes its own
// 128x96 gx slice in the preamble via the same MFMA fragment stream as
// phase_reg (A from xb rows, B from WxF in swzW layout). Output lands
// directly in the gxr/gxz/gxn registers (C layout row=quad*4+reg, col=m16
// matches). Eliminates k_gx kernel + gxb traffic entirely.
// ---------------------------------------------------------------------------
__device__ __forceinline__ void gbar2(unsigned* flags, int j, unsigned target,
                                      bool fast, int tid)
{
    WAITVM(0);                     // own data stores acked at L2
    __syncthreads();
    if (tid < 64) {
        if (tid == 0) {
            if (!fast) __threadfence();   // release (L2 writeback) — slow path
            __hip_atomic_store(flags + j, target, __ATOMIC_RELAXED,
                               __HIP_MEMORY_SCOPE_AGENT);
        }
        unsigned v; int guard = 0;
        do {
            v = (tid < 16) ? __hip_atomic_load(flags + tid, __ATOMIC_RELAXED,
                                               __HIP_MEMORY_SCOPE_AGENT)
                           : target;
        } while (__ballot(v >= target) != ~0ull && ++guard < (1 << 18));
        if (!fast) { if (tid == 0) __threadfence(); }   // acquire — slow path
        else asm volatile("buffer_inv" ::: "memory");   // L1-only invalidate
    }
    __syncthreads();
}

// A(16 rows x 512, row stride 512) @ resident-W frags [f0..f0+NF) -> acc[NF]
template<int NF>
__device__ __forceinline__ void phase_reg(
    const short* __restrict__ srcw, const short* __restrict__ wl,
    int f0, int lane, floatx4 (&acc)[NF])
{
    const short* g = srcw + (size_t)(lane & 15) * 512 + (lane >> 4) * 8;
    short8 a[16];
#pragma unroll
    for (int kc = 0; kc < 16; ++kc)
        a[kc] = *(const short8*)(g + kc * 32);
#pragma unroll
    for (int kc = 0; kc < 16; ++kc) {
        short8 bfr[NF];
#pragma unroll
        for (int f = 0; f < NF; ++f)
            bfr[f] = *(short8*)(wl + ((kc * 6 + f0 + f) << 9) + lane * 8);
#pragma unroll
        for (int f = 0; f < NF; ++f)
            acc[f] = __builtin_amdgcn_mfma_f32_16x16x32_bf16(a[kc], bfr[f],
                                                             acc[f], 0, 0, 0);
    }
}

__global__ __launch_bounds__(512, 2) void k_gru15(
    const bf16* __restrict__ Wfrag, const bf16* __restrict__ WxF,
    const bf16* __restrict__ xb,
    const float* __restrict__ br, const float* __restrict__ bz,
    const float* __restrict__ bn,
    bf16* __restrict__ hs, bf16* __restrict__ rhb,
    unsigned* __restrict__ ctr, int* __restrict__ xcdtab)
{
    __shared__ short wlds[6 * 16 * 512];   // 96 KB resident weight slice
    const int tid = threadIdx.x;
    const int wave = tid >> 6, lane = tid & 63;
    const int m16 = lane & 15, quad = lane >> 4;
    const int b = blockIdx.x;
    const int s = b >> 3;
    const int m = (b & 7) + ((s & 1) << 3);   // row-group 0..15
    const int j = s >> 1;                     // col-slice 0..15
    const int wrow = wave * 16;
    unsigned* flg  = ctr + m * 32;            // main flags [0..15]
    unsigned* vflg = ctr + m * 32 + 16;       // verify flags [16..31]

    int myxcd;
    asm volatile("s_getreg_b32 %0, hwreg(HW_REG_XCC_ID)" : "=s"(myxcd));
    myxcd &= 15;
    if (tid == 0) xcdtab[m * 16 + j] = myxcd;

    // ---- fused gx: 128x96 slice via MFMA (A = xb rows, B = WxF frags) ----
    floatx4 ga[6];
#pragma unroll
    for (int f = 0; f < 6; ++f) ga[f] = (floatx4)0.0f;
    {
        const short* xg = (const short*)xb +
            (size_t)(m * 128 + wrow + m16) * 512 + quad * 8;
        const short* wxg = (const short*)WxF + (size_t)j * 49152 + lane * 8;
#pragma unroll
        for (int kc = 0; kc < 16; ++kc) {
            short8 a = *(const short8*)(xg + kc * 32);
            short8 bfr[6];
#pragma unroll
            for (int f = 0; f < 6; ++f)
                bfr[f] = *(const short8*)(wxg + ((kc * 6 + f) << 9));
#pragma unroll
            for (int f = 0; f < 6; ++f)
                ga[f] = __builtin_amdgcn_mfma_f32_16x16x32_bf16(a, bfr[f],
                                                                ga[f], 0, 0, 0);
        }
    }

    // one-time resident weight preload (96 KB) — issued after gx loads so
    // the gx loads' implicit waits don't drain the DMA queue
    const short* wsrc = (const short*)Wfrag + (size_t)j * 49152;
#pragma unroll
    for (int r = 0; r < 12; ++r)
        ll16(wsrc + ((wave * 12 + r) << 9) + lane * 8, wlds + ((wave * 12 + r) << 9));

    // bias add -> step-invariant gx registers
    float gxr[2][4], gxz[2][4], gxn[2][4];
#pragma unroll
    for (int fc = 0; fc < 2; ++fc) {
        int col = j * 32 + fc * 16 + m16;
        float vbr = br[col], vbz = bz[col], vbn = bn[col];
#pragma unroll
        for (int reg = 0; reg < 4; ++reg) {
            gxr[fc][reg] = ga[fc][reg] + vbr;
            gxz[fc][reg] = ga[2 + fc][reg] + vbz;
            gxn[fc][reg] = ga[4 + fc][reg] + vbn;
        }
    }

    // verify barrier (full fences, once; WAITVM(0) drains weight DMA)
    gbar2(vflg, j, 1u, false, tid);
    bool fast = true;
#pragma unroll
    for (int jj = 0; jj < 16; ++jj) {
        int xv = __hip_atomic_load((const int*)xcdtab + m * 16 + jj,
                                   __ATOMIC_RELAXED, __HIP_MEMORY_SCOPE_AGENT);
        fast = fast && (xv == myxcd);
    }

    float h32[2][4];
    float zf[2][4];
    unsigned nbar = 0;
    const int rowg = m * 128 + wrow + quad * 4;

    // ---- t = 0: h = 0 -> h1 = (1-sigm(gxz)) * tanh(gxn) ----
#pragma unroll
    for (int fc = 0; fc < 2; ++fc)
#pragma unroll
        for (int reg = 0; reg < 4; ++reg) {
            float z = sigm(gxz[fc][reg]);
            float nv = tanhf(gxn[fc][reg]);
            float hn = (1.0f - z) * nv;
            h32[fc][reg] = hn;
            hs[(size_t)(rowg + reg) * 512 + j * 32 + fc * 16 + m16] = (bf16)hn;
        }
    ++nbar; gbar2(flg, j, nbar, fast, tid);

    for (int t = 1; t < LDIM; ++t) {
        // ---- phase 1: r,z = sigm(h @ W_hr|W_hz + gx); rh -> rhb ----
        floatx4 acc[4];
#pragma unroll
        for (int f = 0; f < 4; ++f) acc[f] = (floatx4)0.0f;
        phase_reg<4>((const short*)hs + ((size_t)(t - 1) * BDIM + m * 128 + wrow) * 512,
                     wlds, 0, lane, acc);
#pragma unroll
        for (int fc = 0; fc < 2; ++fc)
#pragma unroll
            for (int reg = 0; reg < 4; ++reg) {
                float r = sigm(acc[fc][reg] + gxr[fc][reg]);
                zf[fc][reg] = sigm(acc[2 + fc][reg] + gxz[fc][reg]);
                rhb[(size_t)(rowg + reg) * 512 + j * 32 + fc * 16 + m16] =
                    (bf16)(r * h32[fc][reg]);
            }
        ++nbar; gbar2(flg, j, nbar, fast, tid);   // rh panel complete
        // ---- phase 2: n = tanh(rh @ W_hn + gxn); h update; hs[t] ----
        floatx4 acc2[2];
#pragma unroll
        for (int f = 0; f < 2; ++f) acc2[f] = (floatx4)0.0f;
        phase_reg<2>((const short*)rhb + (size_t)(m * 128 + wrow) * 512,
                     wlds, 4, lane, acc2);
#pragma unroll
        for (int fc = 0; fc < 2; ++fc)
#pragma unroll
            for (int reg = 0; reg < 4; ++reg) {
                float nv = tanhf(acc2[fc][reg] + gxn[fc][reg]);
                float z = zf[fc][reg];
                float hn = (1.0f - z) * nv + z * h32[fc][reg];
                h32[fc][reg] = hn;
                hs[((size_t)t * BDIM + rowg + reg) * 512 + j * 32 + fc * 16 + m16] =
                    (bf16)hn;
            }
        if (t < LDIM - 1) { ++nbar; gbar2(flg, j, nbar, fast, tid); }  // hs[t] done
    }
}

// ---------------------------------------------------------------------------
// Multiscale conv as MFMA GEMM + bias + PReLU -> y bf16 (B, L, 512)
// 1D grid 1280: btile XCD-pinned, g decoded heavy-first (r12 proven).
// ---------------------------------------------------------------------------
__global__ __launch_bounds__(256) void k_conv(
    const bf16* __restrict__ hs, const bf16* __restrict__ Wc_t,
    const float* __restrict__ b1, const float* __restrict__ b3,
    const float* __restrict__ b5, const float* __restrict__ b7,
    const float* __restrict__ pa, bf16* __restrict__ y)
{
    __shared__ short lds[2 * 128 * 32];
    const int tid = threadIdx.x;
    const int bid = blockIdx.x;          // 0..1279
    const int xcd = bid & 7;
    const int idx = bid >> 3;            // 0..159
    const int half = idx / 80;           // 0,1
    const int btile = xcd + 8 * half;    // hs panel pinned to this XCD
    const int gl = idx % 80;
    const int g = 3 - (gl / 20);         // heavy-first: g=3 dispatched first
    const int l = gl % 20;
    const int row0 = btile * 128;
    const int ktap = 2 * g + 1, p = g;
    const int offs[4] = {0, 65536, 262144, 589824};
    const short* Wg = (const short*)Wc_t + offs[g];
    floatx4 acc[4][4];
#pragma unroll
    for (int i = 0; i < 4; ++i)
#pragma unroll
        for (int j = 0; j < 4; ++j) acc[i][j] = (floatx4)0.0f;
    for (int tap = 0; tap < ktap; ++tap) {
        int li = l + tap - p;
        if (li < 0 || li >= LDIM) continue;
        gemm_tile_ll((const short*)hs + (size_t)li * BDIM * HDIM + (size_t)row0 * 512, 512,
                     Wg + (size_t)tap * 128 * 512, 512, 512, lds, acc, tid);
    }
    const float* bp = (g == 0) ? b1 : (g == 1) ? b3 : (g == 2) ? b5 : b7;
    const float a = *pa;
    const int wave = tid >> 6, lane = tid & 63;
    const int wm = wave & 1, wn = wave >> 1;
    const int m16 = lane & 15, quad = lane >> 4;
#pragma unroll
    for (int i = 0; i < 4; ++i)
#pragma unroll
        for (int j = 0; j < 4; ++j)
#pragma unroll
            for (int reg = 0; reg < 4; ++reg) {
                int b = row0 + wm * 64 + i * 16 + quad * 4 + reg;
                int col = wn * 64 + j * 16 + m16;
                float v = acc[i][j][reg] + bp[col];
                v = (v >= 0.0f) ? v : a * v;
                y[((size_t)b * LDIM + l) * 512 + g * 128 + col] = (bf16)v;
            }
}

// ---------------------------------------------------------------------------
// Head as MFMA GEMM: (40960 x 64) = y(40960x512) @ [Wmu|Wstd]^T, fused
// sample+lp. ll16-staged; lp reduced straight into out_lp via atomics
// (k_final eliminated; out_lp zeroed in prep).
// ---------------------------------------------------------------------------
__global__ __launch_bounds__(256) void k_head2(
    const bf16* __restrict__ y, const bf16* __restrict__ Wh_t,
    const float* __restrict__ bmu, const float* __restrict__ bstd,
    const float* __restrict__ eps, float* __restrict__ out_comm,
    float* __restrict__ out_lp)
{
    __shared__ short As[128 * 32];
    __shared__ short Bs[64 * 32];
    const int tid = threadIdx.x;
    const int wave = tid >> 6, lane = tid & 63;
    const int m16 = lane & 15, quad = lane >> 4;
    const int lrow = lane >> 2, lcol = (lane & 3) * 8;
    const int row0 = blockIdx.x * 128;
    floatx4 acc[2][4];
#pragma unroll
    for (int i = 0; i < 2; ++i)
#pragma unroll
        for (int j = 0; j < 4; ++j) acc[i][j] = (floatx4)0.0f;
    const short* Ap = (const short*)y + (size_t)row0 * 512;
    const short* Bp = (const short*)Wh_t;
    for (int k0 = 0; k0 < 512; k0 += 32) {
        __syncthreads();
        ll16(Ap + (size_t)(wave * 16 + lrow) * 512 + k0 + lcol, As + wave * 512);
        ll16(Ap + (size_t)((wave + 4) * 16 + lrow) * 512 + k0 + lcol,
             As + (wave + 4) * 512);
        ll16(Bp + (size_t)(wave * 16 + lrow) * 512 + k0 + lcol, Bs + wave * 512);
        WAITVM(0);
        __syncthreads();
        short8 af[2], bfr[4];
#pragma unroll
        for (int i = 0; i < 2; ++i)
            af[i] = *(short8*)(As + (wave * 32 + i * 16 + m16) * 32 + quad * 8);
#pragma unroll
        for (int j = 0; j < 4; ++j)
            bfr[j] = *(short8*)(Bs + (j * 16 + m16) * 32 + quad * 8);
#pragma unroll
        for (int i = 0; i < 2; ++i)
#pragma unroll
            for (int j = 0; j < 4; ++j)
                acc[i][j] = __builtin_amdgcn_mfma_f32_16x16x32_bf16(
                    af[i], bfr[j], acc[i][j], 0, 0, 0);
    }
#pragma unroll
    for (int i = 0; i < 2; ++i)
#pragma unroll
        for (int reg = 0; reg < 4; ++reg) {
            int row = row0 + wave * 32 + i * 16 + quad * 4 + reg;
            float lp = 0.0f;
#pragma unroll
            for (int jj = 0; jj < 2; ++jj) {
                int c = jj * 16 + m16;
                float mu = acc[i][jj][reg] + bmu[c];
                float sraw = acc[i][jj + 2][reg] + bstd[c];
                float sp = (sraw > 20.0f) ? sraw : log1pf(expf(sraw));
                float sd = fminf(fmaxf(sp, 2.0611536e-09f), 7.389056f);
                float e = eps[(size_t)row * 32 + c];
                float comm = fmaf(e, sd, mu);
                float tt = tanhf(comm);
                out_comm[(size_t)row * 32 + c] = tt;
                lp += -0.5f * e * e - logf(sd) - 0.91893853320467274f
                      - logf(1.0f - tt * tt + 1e-6f);
            }
            lp += __shfl_xor(lp, 1, 16);
            lp += __shfl_xor(lp, 2, 16);
            lp += __shfl_xor(lp, 4, 16);
            lp += __shfl_xor(lp, 8, 16);
            if (m16 == 0)
                atomicAdd(out_lp + row / LDIM, lp * (1.0f / (LDIM * CDIM)));
        }
}

// ---------------------------------------------------------------------------
extern "C" void kernel_launch(void* const* d_in, const int* in_sizes, int n_in,
                              void* d_out, int out_size, void* d_ws, size_t ws_size,
                              hipStream_t stream)
{
    const float* x    = (const float*)d_in[0];
    const float* Wr   = (const float*)d_in[1];
    const float* br   = (const float*)d_in[2];
    const float* Wz   = (const float*)d_in[3];
    const float* bz   = (const float*)d_in[4];
    const float* Wn   = (const float*)d_in[5];
    const float* bn   = (const float*)d_in[6];
    const float* w1   = (const float*)d_in[7];
    const float* b1   = (const float*)d_in[8];
    const float* w3   = (const float*)d_in[9];
    const float* b3   = (const float*)d_in[10];
    const float* w5   = (const float*)d_in[11];
    const float* b5   = (const float*)d_in[12];
    const float* w7   = (const float*)d_in[13];
    const float* b7   = (const float*)d_in[14];
    const float* pa   = (const float*)d_in[15];
    const float* Wmu  = (const float*)d_in[16];
    const float* bmu  = (const float*)d_in[17];
    const float* Wstd = (const float*)d_in[18];
    const float* bstd = (const float*)d_in[19];
    const float* eps  = (const float*)d_in[20];

    char* cur = (char*)d_ws;
    auto alloc = [&](size_t bytes) -> void* {
        void* r = (void*)cur;
        cur += (bytes + 255) & ~(size_t)255;
        return r;
    };
    const size_t BH = (size_t)BDIM * HDIM;
    bf16*  xb    = (bf16*)alloc(BH * 2);
    bf16*  hs    = (bf16*)alloc(BH * LDIM * 2);
    bf16*  ybuf  = (bf16*)alloc(BH * LDIM * 2);
    bf16*  Wfrag = (bf16*)alloc((size_t)786432 * 2);
    bf16*  WxF   = (bf16*)alloc((size_t)786432 * 2);
    bf16*  Wc_t  = (bf16*)alloc((size_t)1048576 * 2);
    bf16*  Wh_t  = (bf16*)alloc((size_t)64 * 512 * 2);
    bf16*  rhb   = (bf16*)alloc((size_t)BDIM * 512 * 2);
    unsigned* ctr = (unsigned*)alloc(2048);
    int*   xcdtab = (int*)alloc(1024);

    float* out_comm = (float*)d_out;
    float* out_lp   = (float*)d_out + (size_t)BDIM * LDIM * CDIM;

    // one launch: all preps + swizzles + out_lp/ctr zeroing
    k_prep_all<<<14473, 256, 0, stream>>>(x, xb, Wr, Wz, Wn, Wfrag,
                                          w1, w3, w5, w7, Wc_t, Wmu, Wstd,
                                          Wh_t, WxF, out_lp, ctr);

    // 256 blocks, 1/CU (96KB LDS) on 256 CUs -> co-resident; spins bounded
    k_gru15<<<256, 512, 0, stream>>>(Wfrag, WxF, xb, br, bz, bn,
                                     hs, rhb, ctr, xcdtab);

    k_conv<<<1280, 256, 0, stream>>>(hs, Wc_t, b1, b3, b5, b7, pa, ybuf);

    k_head2<<<320, 256, 0, stream>>>(ybuf, Wh_t, bmu, bstd, eps,
                                     out_comm, out_lp);
}

// Round 14
// 470.504 us; speedup vs baseline: 1.0115x; 1.0115x over previous
//
#include <hip/hip_runtime.h>
#include <hip/hip_bf16.h>

typedef __hip_bfloat16 bf16;
typedef short short8 __attribute__((ext_vector_type(8)));
typedef float floatx4 __attribute__((ext_vector_type(4)));

#define BDIM 2048   // E*S
#define HDIM 512
#define LDIM 20
#define CDIM 32

__device__ __forceinline__ float sigm(float x) { return 1.0f / (1.0f + expf(-x)); }

// async global->LDS, 16 B per lane; lds base must be wave-uniform, HW strides by lane*16
__device__ __forceinline__ void ll16(const short* g, short* l)
{
    __builtin_amdgcn_global_load_lds(
        (const __attribute__((address_space(1))) void*)g,
        (__attribute__((address_space(3))) void*)l, 16, 0, 0);
}
#define WAITVM(N) asm volatile("s_waitcnt vmcnt(" #N ")" ::: "memory")

// ---------------------------------------------------------------------------
// 128x128 bf16 MFMA tile with global_load_lds staging (m97 structure):
// linear LDS chunks [128][32] (64B rows -> 2-way bank aliasing, free).
// ---------------------------------------------------------------------------
__device__ __forceinline__ void gemm_tile_ll(
    const short* __restrict__ A, int lda,
    const short* __restrict__ Bt, int ldb,
    int K, short* lds, floatx4 (&acc)[4][4], int tid)
{
    short* As = lds;             // [128][32] linear
    short* Bs = lds + 128 * 32;  // [128][32] linear
    const int wave = tid >> 6, lane = tid & 63;
    const int wm = wave & 1, wn = wave >> 1;
    const int m16 = lane & 15, quad = lane >> 4;
    const int lrow = lane >> 2;          // 0..15 (16 rows per wave-issue)
    const int lcol = (lane & 3) * 8;     // 4 x 16B per row

    for (int k0 = 0; k0 < K; k0 += 32) {
        __syncthreads();                 // previous chunk's reads retired
#pragma unroll
        for (int seg = 0; seg < 2; ++seg) {
            const int sg = wave + seg * 4;   // 0..7: 16-row segment
            ll16(A  + (size_t)(sg * 16 + lrow) * lda + k0 + lcol, As + sg * 512);
            ll16(Bt + (size_t)(sg * 16 + lrow) * ldb + k0 + lcol, Bs + sg * 512);
        }
        WAITVM(0);
        __syncthreads();                 // chunk staged by all waves
        short8 af[4], bfr[4];
#pragma unroll
        for (int i = 0; i < 4; ++i)
            af[i] = *(short8*)(As + (wm * 64 + i * 16 + m16) * 32 + quad * 8);
#pragma unroll
        for (int j = 0; j < 4; ++j)
            bfr[j] = *(short8*)(Bs + (wn * 64 + j * 16 + m16) * 32 + quad * 8);
#pragma unroll
        for (int i = 0; i < 4; ++i)
#pragma unroll
            for (int j = 0; j < 4; ++j)
                acc[i][j] = __builtin_amdgcn_mfma_f32_16x16x32_bf16(
                    af[i], bfr[j], acc[i][j], 0, 0, 0);
    }
}

// ---------------------------------------------------------------------------
// Merged prep: xb cast | swzW (h-half) | wc reorder | wh transpose |
// swzX (x-half, for in-GRU gx) | out_lp zero | ctr zero. One launch.
// ---------------------------------------------------------------------------
__global__ __launch_bounds__(256) void k_prep_all(
    const float* __restrict__ x, bf16* __restrict__ xb,
    const float* __restrict__ Wr, const float* __restrict__ Wz,
    const float* __restrict__ Wn, bf16* __restrict__ Wfrag,
    const float* __restrict__ w1, const float* __restrict__ w3,
    const float* __restrict__ w5, const float* __restrict__ w7,
    bf16* __restrict__ wt,
    const float* __restrict__ Wmu, const float* __restrict__ Wstd,
    bf16* __restrict__ Wh_t, bf16* __restrict__ WxF,
    float* __restrict__ out_lp, unsigned* __restrict__ ctr)
{
    const int bid = blockIdx.x, tid = threadIdx.x;
    if (bid < 4096) {                       // xb: x -> bf16
        int i = bid * 256 + tid;
        xb[i] = (bf16)x[i];
    } else if (bid < 7168) {                // swzW: h-half GRU weights
        int idx = (bid - 4096) * 256 + tid; // 0..786431
        int e = idx & 7, lane = (idx >> 3) & 63;
        int t2 = idx >> 9;                  // (j*16 + kc)*6 + f
        int f = t2 % 6, jk = t2 / 6;
        int kc = jk & 15, j = jk >> 4;
        int ftype = f >> 1;
        int col = j * 32 + (f & 1) * 16 + (lane & 15);
        int k = kc * 32 + ((lane >> 4) << 3) + e;
        const float* W = (ftype == 0) ? Wr : (ftype == 1) ? Wz : Wn;
        Wfrag[idx] = (bf16)W[(size_t)(512 + k) * 512 + col];
    } else if (bid < 11264) {               // wc: conv weights reorder
        int idx = (bid - 7168) * 256 + tid;
        int g, base;
        if (idx < 65536)       { g = 0; base = 0;      }
        else if (idx < 262144) { g = 1; base = 65536;  }
        else if (idx < 589824) { g = 2; base = 262144; }
        else                   { g = 3; base = 589824; }
        int rel = idx - base;
        int k = 2 * g + 1;
        int ci = rel & 511;
        int t2 = rel >> 9;
        int co = t2 & 127;
        int tap = t2 >> 7;
        const float* w = (g == 0) ? w1 : (g == 1) ? w3 : (g == 2) ? w5 : w7;
        wt[idx] = (bf16)w[((size_t)co * 512 + ci) * k + tap];
    } else if (bid < 11392) {               // wh: [Wmu|Wstd] -> [64][512]
        int idx = (bid - 11264) * 256 + tid; // 0..32767
        int n = idx >> 9, k = idx & 511;
        float v = (n < 32) ? Wmu[(size_t)k * 32 + n]
                           : Wstd[(size_t)k * 32 + (n - 32)];
        Wh_t[idx] = (bf16)v;
    } else if (bid < 14464) {               // swzX: x-half weights (gx in GRU)
        int idx = (bid - 11392) * 256 + tid; // 0..786431
        int e = idx & 7, lane = (idx >> 3) & 63;
        int t2 = idx >> 9;
        int f = t2 % 6, jk = t2 / 6;
        int kc = jk & 15, j = jk >> 4;
        int ftype = f >> 1;
        int col = j * 32 + (f & 1) * 16 + (lane & 15);
        int k = kc * 32 + ((lane >> 4) << 3) + e;   // rows 0..511 (x-half)
        const float* W = (ftype == 0) ? Wr : (ftype == 1) ? Wz : Wn;
        WxF[idx] = (bf16)W[(size_t)k * 512 + col];
    } else if (bid < 14472) {               // out_lp zero (2048 floats)
        out_lp[(bid - 14464) * 256 + tid] = 0.0f;
    } else {                                // ctr zero (512 dwords)
        ctr[tid * 2]     = 0u;
        ctr[tid * 2 + 1] = 0u;
    }
}

// ---------------------------------------------------------------------------
// GRU v16 = v9 sync (PROVEN, closed) + fused gx with LDS-STAGED B-fragments:
// r13's regression was per-wave redundant global B reads (8x 96KB/block).
// v16 DMAs the WxF slice into wlds first (wlds is free pre-Wfrag), computes
// gx via the proven phase_reg<6> path, then overwrites wlds with Wfrag.
// ---------------------------------------------------------------------------
__device__ __forceinline__ void gbar2(unsigned* flags, int j, unsigned target,
                                      bool fast, int tid)
{
    WAITVM(0);                     // own data stores acked at L2
    __syncthreads();
    if (tid < 64) {
        if (tid == 0) {
            if (!fast) __threadfence();   // release (L2 writeback) — slow path
            __hip_atomic_store(flags + j, target, __ATOMIC_RELAXED,
                               __HIP_MEMORY_SCOPE_AGENT);
        }
        unsigned v; int guard = 0;
        do {
            v = (tid < 16) ? __hip_atomic_load(flags + tid, __ATOMIC_RELAXED,
                                               __HIP_MEMORY_SCOPE_AGENT)
                           : target;
        } while (__ballot(v >= target) != ~0ull && ++guard < (1 << 18));
        if (!fast) { if (tid == 0) __threadfence(); }   // acquire — slow path
        else asm volatile("buffer_inv" ::: "memory");   // L1-only invalidate
    }
    __syncthreads();
}

// A(16 rows x 512, row stride 512) @ resident-W frags [f0..f0+NF) -> acc[NF]
template<int NF>
__device__ __forceinline__ void phase_reg(
    const short* __restrict__ srcw, const short* __restrict__ wl,
    int f0, int lane, floatx4 (&acc)[NF])
{
    const short* g = srcw + (size_t)(lane & 15) * 512 + (lane >> 4) * 8;
    short8 a[16];
#pragma unroll
    for (int kc = 0; kc < 16; ++kc)
        a[kc] = *(const short8*)(g + kc * 32);
#pragma unroll
    for (int kc = 0; kc < 16; ++kc) {
        short8 bfr[NF];
#pragma unroll
        for (int f = 0; f < NF; ++f)
            bfr[f] = *(short8*)(wl + ((kc * 6 + f0 + f) << 9) + lane * 8);
#pragma unroll
        for (int f = 0; f < NF; ++f)
            acc[f] = __builtin_amdgcn_mfma_f32_16x16x32_bf16(a[kc], bfr[f],
                                                             acc[f], 0, 0, 0);
    }
}

__global__ __launch_bounds__(512, 2) void k_gru16(
    const bf16* __restrict__ Wfrag, const bf16* __restrict__ WxF,
    const bf16* __restrict__ xb,
    const float* __restrict__ br, const float* __restrict__ bz,
    const float* __restrict__ bn,
    bf16* __restrict__ hs, bf16* __restrict__ rhb,
    unsigned* __restrict__ ctr, int* __restrict__ xcdtab)
{
    __shared__ short wlds[6 * 16 * 512];   // 96 KB: WxF slice, then Wfrag
    const int tid = threadIdx.x;
    const int wave = tid >> 6, lane = tid & 63;
    const int m16 = lane & 15, quad = lane >> 4;
    const int b = blockIdx.x;
    const int s = b >> 3;
    const int m = (b & 7) + ((s & 1) << 3);   // row-group 0..15
    const int j = s >> 1;                     // col-slice 0..15
    const int wrow = wave * 16;
    unsigned* flg  = ctr + m * 32;            // main flags [0..15]
    unsigned* vflg = ctr + m * 32 + 16;       // verify flags [16..31]

    int myxcd;
    asm volatile("s_getreg_b32 %0, hwreg(HW_REG_XCC_ID)" : "=s"(myxcd));
    myxcd &= 15;
    if (tid == 0) xcdtab[m * 16 + j] = myxcd;

    // ---- stage WxF slice into wlds (proven ll16 path) ----
    const short* wxsrc = (const short*)WxF + (size_t)j * 49152;
#pragma unroll
    for (int r = 0; r < 12; ++r)
        ll16(wxsrc + ((wave * 12 + r) << 9) + lane * 8, wlds + ((wave * 12 + r) << 9));
    WAITVM(0);
    __syncthreads();

    // ---- fused gx: 128x96 slice via phase_reg<6> (B from LDS) ----
    floatx4 ga[6];
#pragma unroll
    for (int f = 0; f < 6; ++f) ga[f] = (floatx4)0.0f;
    phase_reg<6>((const short*)xb + ((size_t)m * 128 + wrow) * 512,
                 wlds, 0, lane, ga);
    __syncthreads();   // all wlds reads retired before overwrite

    // ---- resident Wfrag preload (drained by verify barrier's WAITVM) ----
    const short* wsrc = (const short*)Wfrag + (size_t)j * 49152;
#pragma unroll
    for (int r = 0; r < 12; ++r)
        ll16(wsrc + ((wave * 12 + r) << 9) + lane * 8, wlds + ((wave * 12 + r) << 9));

    // bias add -> step-invariant gx registers
    float gxr[2][4], gxz[2][4], gxn[2][4];
#pragma unroll
    for (int fc = 0; fc < 2; ++fc) {
        int col = j * 32 + fc * 16 + m16;
        float vbr = br[col], vbz = bz[col], vbn = bn[col];
#pragma unroll
        for (int reg = 0; reg < 4; ++reg) {
            gxr[fc][reg] = ga[fc][reg] + vbr;
            gxz[fc][reg] = ga[2 + fc][reg] + vbz;
            gxn[fc][reg] = ga[4 + fc][reg] + vbn;
        }
    }

    // verify barrier (full fences, once; WAITVM(0) drains Wfrag DMA)
    gbar2(vflg, j, 1u, false, tid);
    bool fast = true;
#pragma unroll
    for (int jj = 0; jj < 16; ++jj) {
        int xv = __hip_atomic_load((const int*)xcdtab + m * 16 + jj,
                                   __ATOMIC_RELAXED, __HIP_MEMORY_SCOPE_AGENT);
        fast = fast && (xv == myxcd);
    }

    float h32[2][4];
    float zf[2][4];
    unsigned nbar = 0;
    const int rowg = m * 128 + wrow + quad * 4;

    // ---- t = 0: h = 0 -> h1 = (1-sigm(gxz)) * tanh(gxn) ----
#pragma unroll
    for (int fc = 0; fc < 2; ++fc)
#pragma unroll
        for (int reg = 0; reg < 4; ++reg) {
            float z = sigm(gxz[fc][reg]);
            float nv = tanhf(gxn[fc][reg]);
            float hn = (1.0f - z) * nv;
            h32[fc][reg] = hn;
            hs[(size_t)(rowg + reg) * 512 + j * 32 + fc * 16 + m16] = (bf16)hn;
        }
    ++nbar; gbar2(flg, j, nbar, fast, tid);

    for (int t = 1; t < LDIM; ++t) {
        // ---- phase 1: r,z = sigm(h @ W_hr|W_hz + gx); rh -> rhb ----
        floatx4 acc[4];
#pragma unroll
        for (int f = 0; f < 4; ++f) acc[f] = (floatx4)0.0f;
        phase_reg<4>((const short*)hs + ((size_t)(t - 1) * BDIM + m * 128 + wrow) * 512,
                     wlds, 0, lane, acc);
#pragma unroll
        for (int fc = 0; fc < 2; ++fc)
#pragma unroll
            for (int reg = 0; reg < 4; ++reg) {
                float r = sigm(acc[fc][reg] + gxr[fc][reg]);
                zf[fc][reg] = sigm(acc[2 + fc][reg] + gxz[fc][reg]);
                rhb[(size_t)(rowg + reg) * 512 + j * 32 + fc * 16 + m16] =
                    (bf16)(r * h32[fc][reg]);
            }
        ++nbar; gbar2(flg, j, nbar, fast, tid);   // rh panel complete
        // ---- phase 2: n = tanh(rh @ W_hn + gxn); h update; hs[t] ----
        floatx4 acc2[2];
#pragma unroll
        for (int f = 0; f < 2; ++f) acc2[f] = (floatx4)0.0f;
        phase_reg<2>((const short*)rhb + (size_t)(m * 128 + wrow) * 512,
                     wlds, 4, lane, acc2);
#pragma unroll
        for (int fc = 0; fc < 2; ++fc)
#pragma unroll
            for (int reg = 0; reg < 4; ++reg) {
                float nv = tanhf(acc2[fc][reg] + gxn[fc][reg]);
                float z = zf[fc][reg];
                float hn = (1.0f - z) * nv + z * h32[fc][reg];
                h32[fc][reg] = hn;
                hs[((size_t)t * BDIM + rowg + reg) * 512 + j * 32 + fc * 16 + m16] =
                    (bf16)hn;
            }
        if (t < LDIM - 1) { ++nbar; gbar2(flg, j, nbar, fast, tid); }  // hs[t] done
    }
}

// ---------------------------------------------------------------------------
// Multiscale conv as MFMA GEMM + bias + PReLU -> y bf16 (B, L, 512)
// 1D grid 1280: btile XCD-pinned, g decoded heavy-first (r12 proven).
// ---------------------------------------------------------------------------
__global__ __launch_bounds__(256) void k_conv(
    const bf16* __restrict__ hs, const bf16* __restrict__ Wc_t,
    const float* __restrict__ b1, const float* __restrict__ b3,
    const float* __restrict__ b5, const float* __restrict__ b7,
    const float* __restrict__ pa, bf16* __restrict__ y)
{
    __shared__ short lds[2 * 128 * 32];
    const int tid = threadIdx.x;
    const int bid = blockIdx.x;          // 0..1279
    const int xcd = bid & 7;
    const int idx = bid >> 3;            // 0..159
    const int half = idx / 80;           // 0,1
    const int btile = xcd + 8 * half;    // hs panel pinned to this XCD
    const int gl = idx % 80;
    const int g = 3 - (gl / 20);         // heavy-first: g=3 dispatched first
    const int l = gl % 20;
    const int row0 = btile * 128;
    const int ktap = 2 * g + 1, p = g;
    const int offs[4] = {0, 65536, 262144, 589824};
    const short* Wg = (const short*)Wc_t + offs[g];
    floatx4 acc[4][4];
#pragma unroll
    for (int i = 0; i < 4; ++i)
#pragma unroll
        for (int j = 0; j < 4; ++j) acc[i][j] = (floatx4)0.0f;
    for (int tap = 0; tap < ktap; ++tap) {
        int li = l + tap - p;
        if (li < 0 || li >= LDIM) continue;
        gemm_tile_ll((const short*)hs + (size_t)li * BDIM * HDIM + (size_t)row0 * 512, 512,
                     Wg + (size_t)tap * 128 * 512, 512, 512, lds, acc, tid);
    }
    const float* bp = (g == 0) ? b1 : (g == 1) ? b3 : (g == 2) ? b5 : b7;
    const float a = *pa;
    const int wave = tid >> 6, lane = tid & 63;
    const int wm = wave & 1, wn = wave >> 1;
    const int m16 = lane & 15, quad = lane >> 4;
#pragma unroll
    for (int i = 0; i < 4; ++i)
#pragma unroll
        for (int j = 0; j < 4; ++j)
#pragma unroll
            for (int reg = 0; reg < 4; ++reg) {
                int b = row0 + wm * 64 + i * 16 + quad * 4 + reg;
                int col = wn * 64 + j * 16 + m16;
                float v = acc[i][j][reg] + bp[col];
                v = (v >= 0.0f) ? v : a * v;
                y[((size_t)b * LDIM + l) * 512 + g * 128 + col] = (bf16)v;
            }
}

// ---------------------------------------------------------------------------
// Head as MFMA GEMM: (40960 x 64) = y(40960x512) @ [Wmu|Wstd]^T, fused
// sample+lp. ll16-staged; lp reduced straight into out_lp via atomics.
// ---------------------------------------------------------------------------
__global__ __launch_bounds__(256) void k_head2(
    const bf16* __restrict__ y, const bf16* __restrict__ Wh_t,
    const float* __restrict__ bmu, const float* __restrict__ bstd,
    const float* __restrict__ eps, float* __restrict__ out_comm,
    float* __restrict__ out_lp)
{
    __shared__ short As[128 * 32];
    __shared__ short Bs[64 * 32];
    const int tid = threadIdx.x;
    const int wave = tid >> 6, lane = tid & 63;
    const int m16 = lane & 15, quad = lane >> 4;
    const int lrow = lane >> 2, lcol = (lane & 3) * 8;
    const int row0 = blockIdx.x * 128;
    floatx4 acc[2][4];
#pragma unroll
    for (int i = 0; i < 2; ++i)
#pragma unroll
        for (int j = 0; j < 4; ++j) acc[i][j] = (floatx4)0.0f;
    const short* Ap = (const short*)y + (size_t)row0 * 512;
    const short* Bp = (const short*)Wh_t;
    for (int k0 = 0; k0 < 512; k0 += 32) {
        __syncthreads();
        ll16(Ap + (size_t)(wave * 16 + lrow) * 512 + k0 + lcol, As + wave * 512);
        ll16(Ap + (size_t)((wave + 4) * 16 + lrow) * 512 + k0 + lcol,
             As + (wave + 4) * 512);
        ll16(Bp + (size_t)(wave * 16 + lrow) * 512 + k0 + lcol, Bs + wave * 512);
        WAITVM(0);
        __syncthreads();
        short8 af[2], bfr[4];
#pragma unroll
        for (int i = 0; i < 2; ++i)
            af[i] = *(short8*)(As + (wave * 32 + i * 16 + m16) * 32 + quad * 8);
#pragma unroll
        for (int j = 0; j < 4; ++j)
            bfr[j] = *(short8*)(Bs + (j * 16 + m16) * 32 + quad * 8);
#pragma unroll
        for (int i = 0; i < 2; ++i)
#pragma unroll
            for (int j = 0; j < 4; ++j)
                acc[i][j] = __builtin_amdgcn_mfma_f32_16x16x32_bf16(
                    af[i], bfr[j], acc[i][j], 0, 0, 0);
    }
#pragma unroll
    for (int i = 0; i < 2; ++i)
#pragma unroll
        for (int reg = 0; reg < 4; ++reg) {
            int row = row0 + wave * 32 + i * 16 + quad * 4 + reg;
            float lp = 0.0f;
#pragma unroll
            for (int jj = 0; jj < 2; ++jj) {
                int c = jj * 16 + m16;
                float mu = acc[i][jj][reg] + bmu[c];
                float sraw = acc[i][jj + 2][reg] + bstd[c];
                float sp = (sraw > 20.0f) ? sraw : log1pf(expf(sraw));
                float sd = fminf(fmaxf(sp, 2.0611536e-09f), 7.389056f);
                float e = eps[(size_t)row * 32 + c];
                float comm = fmaf(e, sd, mu);
                float tt = tanhf(comm);
                out_comm[(size_t)row * 32 + c] = tt;
                lp += -0.5f * e * e - logf(sd) - 0.91893853320467274f
                      - logf(1.0f - tt * tt + 1e-6f);
            }
            lp += __shfl_xor(lp, 1, 16);
            lp += __shfl_xor(lp, 2, 16);
            lp += __shfl_xor(lp, 4, 16);
            lp += __shfl_xor(lp, 8, 16);
            if (m16 == 0)
                atomicAdd(out_lp + row / LDIM, lp * (1.0f / (LDIM * CDIM)));
        }
}

// ---------------------------------------------------------------------------
extern "C" void kernel_launch(void* const* d_in, const int* in_sizes, int n_in,
                              void* d_out, int out_size, void* d_ws, size_t ws_size,
                              hipStream_t stream)
{
    const float* x    = (const float*)d_in[0];
    const float* Wr   = (const float*)d_in[1];
    const float* br   = (const float*)d_in[2];
    const float* Wz   = (const float*)d_in[3];
    const float* bz   = (const float*)d_in[4];
    const float* Wn   = (const float*)d_in[5];
    const float* bn   = (const float*)d_in[6];
    const float* w1   = (const float*)d_in[7];
    const float* b1   = (const float*)d_in[8];
    const float* w3   = (const float*)d_in[9];
    const float* b3   = (const float*)d_in[10];
    const float* w5   = (const float*)d_in[11];
    const float* b5   = (const float*)d_in[12];
    const float* w7   = (const float*)d_in[13];
    const float* b7   = (const float*)d_in[14];
    const float* pa   = (const float*)d_in[15];
    const float* Wmu  = (const float*)d_in[16];
    const float* bmu  = (const float*)d_in[17];
    const float* Wstd = (const float*)d_in[18];
    const float* bstd = (const float*)d_in[19];
    const float* eps  = (const float*)d_in[20];

    char* cur = (char*)d_ws;
    auto alloc = [&](size_t bytes) -> void* {
        void* r = (void*)cur;
        cur += (bytes + 255) & ~(size_t)255;
        return r;
    };
    const size_t BH = (size_t)BDIM * HDIM;
    bf16*  xb    = (bf16*)alloc(BH * 2);
    bf16*  hs    = (bf16*)alloc(BH * LDIM * 2);
    bf16*  ybuf  = (bf16*)alloc(BH * LDIM * 2);
    bf16*  Wfrag = (bf16*)alloc((size_t)786432 * 2);
    bf16*  WxF   = (bf16*)alloc((size_t)786432 * 2);
    bf16*  Wc_t  = (bf16*)alloc((size_t)1048576 * 2);
    bf16*  Wh_t  = (bf16*)alloc((size_t)64 * 512 * 2);
    bf16*  rhb   = (bf16*)alloc((size_t)BDIM * 512 * 2);
    unsigned* ctr = (unsigned*)alloc(2048);
    int*   xcdtab = (int*)alloc(1024);

    float* out_comm = (float*)d_out;
    float* out_lp   = (float*)d_out + (size_t)BDIM * LDIM * CDIM;

    // one launch: all preps + swizzles + out_lp/ctr zeroing
    k_prep_all<<<14473, 256, 0, stream>>>(x, xb, Wr, Wz, Wn, Wfrag,
                                          w1, w3, w5, w7, Wc_t, Wmu, Wstd,
                                          Wh_t, WxF, out_lp, ctr);

    // 256 blocks, 1/CU (96KB LDS) on 256 CUs -> co-resident; spins bounded
    k_gru16<<<256, 512, 0, stream>>>(Wfrag, WxF, xb, br, bz, bn,
                                     hs, rhb, ctr, xcdtab);

    k_conv<<<1280, 256, 0, stream>>>(hs, Wc_t, b1, b3, b5, b7, pa, ybuf);

    k_head2<<<320, 256, 0, stream>>>(ybuf, Wh_t, bmu, bstd, eps,
                                     out_comm, out_lp);
}